// Round 11
// baseline (189.756 us; speedup 1.0000x reference)
//
#include <hip/hip_runtime.h>
#include <hip/hip_cooperative_groups.h>
#include <cstdint>
#include <cstddef>

namespace cg = cooperative_groups;

// Problem constants
#define B_   4
#define L_   512
#define DIM_ 1024
#define H_   8
#define DQK_ 64
#define DV_  64
#define M_   (B_ * L_)          // 2048 rows
#define EPS_ 1e-5f

typedef __attribute__((ext_vector_type(8))) short short8;
typedef __attribute__((ext_vector_type(4))) float f32x4;

// ---------------------------------------------------------------------------
// bf16 helpers
// ---------------------------------------------------------------------------
__device__ __forceinline__ unsigned short f2bf(float f) {
    uint32_t u = __float_as_uint(f);
    u += 0x7FFFu + ((u >> 16) & 1u);
    return (unsigned short)(u >> 16);
}
__device__ __forceinline__ float bf2f(unsigned short u) {
    return __uint_as_float((uint32_t)u << 16);
}

__device__ __forceinline__ f32x4 mm16(short8 a, short8 b, f32x4 c) {
    return __builtin_amdgcn_mfma_f32_16x16x32_bf16(a, b, c, 0, 0, 0);
}

// 64x64 bf16 plane with XOR swizzle: element (r,c) at byte r*128 + ((2c)^((r&7)<<4))
__device__ __forceinline__ int swoff(int r, int kb) {
    return r * 128 + (kb ^ ((r & 7) << 4));
}
__device__ __forceinline__ short8 frag(const unsigned short* p, int strip, int ks, int lane) {
    const int fr = lane & 15, fq = lane >> 4;
    const int r = strip * 16 + fr;
    return *(const short8*)((const char*)p + swoff(r, ks * 64 + fq * 16));
}

// ---------------------------------------------------------------------------
// Fused cast: x, w_qk|w_v|w_g|w_a -> wall, w_y -> bf16; b_a -> padded bias.
// ---------------------------------------------------------------------------
__global__ __launch_bounds__(256) void cast_all(
    const float* __restrict__ x, const float* __restrict__ wqk,
    const float* __restrict__ wv, const float* __restrict__ wg,
    const float* __restrict__ wy, const float* __restrict__ wa,
    const float* __restrict__ ba,
    unsigned short* __restrict__ xb, unsigned short* __restrict__ wall,
    unsigned short* __restrict__ wyb, float* __restrict__ babias)
{
    const int blk = blockIdx.x;
    if (blk == 7176) {
        if (threadIdx.x < 128)
            babias[threadIdx.x] = (threadIdx.x < 8) ? ba[threadIdx.x] : 0.f;
        return;
    }
    const float* src; unsigned short* dst; int base;
    if      (blk < 2048) { src = x;   dst = xb;                  base = blk; }
    else if (blk < 4096) { src = wqk; dst = wall;                base = blk - 2048; }
    else if (blk < 5120) { src = wv;  dst = wall + 2048 * 1024;  base = blk - 4096; }
    else if (blk < 6144) { src = wg;  dst = wall + 3072 * 1024;  base = blk - 5120; }
    else if (blk < 7168) { src = wy;  dst = wyb;                 base = blk - 6144; }
    else                 { src = wa;  dst = wall + 4096 * 1024;  base = blk - 7168; }
    const int i = base * 256 + threadIdx.x;
    const float4 v = ((const float4*)src)[i];
    ushort4 o;
    o.x = f2bf(v.x); o.y = f2bf(v.y); o.z = f2bf(v.z); o.w = f2bf(v.w);
    ((ushort4*)dst)[i] = o;
}

// ---------------------------------------------------------------------------
// bf16 MFMA GEMM: 128x128 tile, BK=32, 512 threads / 8 waves (2 row x 4 col).
// ---------------------------------------------------------------------------
__device__ __forceinline__ void gload16(const void* g, void* l) {
    __builtin_amdgcn_global_load_lds(
        (const __attribute__((address_space(1))) unsigned int*)g,
        (__attribute__((address_space(3))) unsigned int*)l, 16, 0, 0);
}

__global__ __launch_bounds__(512) void gemm_proj(
    const unsigned short* __restrict__ A, const unsigned short* __restrict__ W,
    const float* __restrict__ bias0, const float* __restrict__ bias1,
    const float* __restrict__ bias2, const float* __restrict__ bias3,
    void* __restrict__ C0, void* __restrict__ C1,
    void* __restrict__ C2, void* __restrict__ C3,
    int n1, int n2, int n3,
    int ld0, int ld1, int ld2, int ld3,
    int bf0, int bf1, int bf2, int bf3,
    int M, int N, int K)
{
    __shared__ unsigned short sA[128 * 32];
    __shared__ unsigned short sB[128 * 32];

    const int t    = threadIdx.x;
    const int lane = t & 63;
    const int wv   = t >> 6;          // 0..7
    const int bm   = blockIdx.y * 128;
    const int bn   = blockIdx.x * 128;
    const int wr   = wv >> 2;
    const int wc   = wv & 3;
    const int fr   = lane & 15;
    const int fq   = lane >> 4;
    const int srow = lane >> 2;
    const int ske  = (lane & 3) * 8;

    f32x4 acc[4][2] = {};

    for (int k0 = 0; k0 < K; k0 += 32) {
        gload16(A + (size_t)(bm + wv * 16 + srow) * K + k0 + ske,
                (char*)sA + wv * 1024);
        gload16(W + (size_t)(bn + wv * 16 + srow) * K + k0 + ske,
                (char*)sB + wv * 1024);
        __syncthreads();

        short8 af[4], bf[2];
#pragma unroll
        for (int mi = 0; mi < 4; ++mi)
            af[mi] = *(const short8*)&sA[(wr * 64 + mi * 16 + fr) * 32 + fq * 8];
#pragma unroll
        for (int ni = 0; ni < 2; ++ni)
            bf[ni] = *(const short8*)&sB[(wc * 32 + ni * 16 + fr) * 32 + fq * 8];
#pragma unroll
        for (int mi = 0; mi < 4; ++mi)
#pragma unroll
            for (int ni = 0; ni < 2; ++ni)
                acc[mi][ni] = mm16(af[mi], bf[ni], acc[mi][ni]);
        __syncthreads();
    }

    void* Cb; const float* bb; int coff, ldc, isbf;
    if      (bn < n1) { Cb = C0; bb = bias0; coff = 0;  ldc = ld0; isbf = bf0; }
    else if (bn < n2) { Cb = C1; bb = bias1; coff = n1; ldc = ld1; isbf = bf1; }
    else if (bn < n3) { Cb = C2; bb = bias2; coff = n2; ldc = ld2; isbf = bf2; }
    else              { Cb = C3; bb = bias3; coff = n3; ldc = ld3; isbf = bf3; }

#pragma unroll
    for (int mi = 0; mi < 4; ++mi)
#pragma unroll
        for (int ni = 0; ni < 2; ++ni) {
            const int col = bn + wc * 32 + ni * 16 + fr - coff;
            const float bv = bb[col];
#pragma unroll
            for (int r = 0; r < 4; ++r) {
                const int row = bm + wr * 64 + mi * 16 + fq * 4 + r;
                const float val = acc[mi][ni][r] + bv;
                if (isbf)
                    ((unsigned short*)Cb)[(size_t)row * ldc + col] = f2bf(val);
                else
                    ((float*)Cb)[(size_t)row * ldc + col] = val;
            }
        }
}

// ---------------------------------------------------------------------------
// y GEMM: 64x64 tile, 4 waves (each 32x32) -> grid (16,32) = 512 blocks.
// ---------------------------------------------------------------------------
__global__ __launch_bounds__(256) void gemm_y(
    const unsigned short* __restrict__ A, const unsigned short* __restrict__ W,
    const float* __restrict__ bias, float* __restrict__ C,
    int M, int N, int K)
{
    __shared__ unsigned short sA[64 * 32];
    __shared__ unsigned short sB[64 * 32];

    const int t    = threadIdx.x;
    const int lane = t & 63;
    const int wv   = t >> 6;
    const int bm   = blockIdx.y * 64;
    const int bn   = blockIdx.x * 64;
    const int wr   = wv >> 1;
    const int wc   = wv & 1;
    const int fr   = lane & 15;
    const int fq   = lane >> 4;
    const int srow = lane >> 2;
    const int ske  = (lane & 3) * 8;

    f32x4 acc[2][2] = {};

    for (int k0 = 0; k0 < K; k0 += 32) {
        gload16(A + (size_t)(bm + wv * 16 + srow) * K + k0 + ske,
                (char*)sA + wv * 1024);
        gload16(W + (size_t)(bn + wv * 16 + srow) * K + k0 + ske,
                (char*)sB + wv * 1024);
        __syncthreads();

        short8 af[2], bf[2];
#pragma unroll
        for (int mi = 0; mi < 2; ++mi)
            af[mi] = *(const short8*)&sA[(wr * 32 + mi * 16 + fr) * 32 + fq * 8];
#pragma unroll
        for (int ni = 0; ni < 2; ++ni)
            bf[ni] = *(const short8*)&sB[(wc * 32 + ni * 16 + fr) * 32 + fq * 8];
#pragma unroll
        for (int mi = 0; mi < 2; ++mi)
#pragma unroll
            for (int ni = 0; ni < 2; ++ni)
                acc[mi][ni] = mm16(af[mi], bf[ni], acc[mi][ni]);
        __syncthreads();
    }

#pragma unroll
    for (int mi = 0; mi < 2; ++mi)
#pragma unroll
        for (int ni = 0; ni < 2; ++ni) {
            const int col = bn + wc * 32 + ni * 16 + fr;
            const float bv = bias[col];
#pragma unroll
            for (int r = 0; r < 4; ++r) {
                const int row = bm + wr * 32 + mi * 16 + fq * 4 + r;
                C[(size_t)row * N + col] = acc[mi][ni][r] + bv;
            }
        }
}

// ---------------------------------------------------------------------------
// fused_chunks (cooperative, grid=256 blocks x 256 threads, 1 block/CU):
// Phase 1 (chunkA): lambda scan, Q~/K~/V planes, P=Q~K~^T masked -> pP planes,
//   h_intra -> registers (hreg), Zloc = G*(K~^T V) -> global, Gbuf.
// grid.sync()
// Phase 2: per-block coalesced redundant prefix scan -> own Zin planes (pKr/pKi
//   reused, transposed+swizzled); block c=7 emits hid_next.
// Phase 3 (chunkC): hreg += Q~.Zin (Q~ planes still in LDS), GroupNorm + SiLU
//   -> act (bf16).
// ---------------------------------------------------------------------------
__global__ __launch_bounds__(256) void fused_chunks(
    const unsigned short* __restrict__ qk_bf,
    const unsigned short* __restrict__ v_bf,
    const float* __restrict__ a_pad,
    const float* __restrict__ p_angle,
    const float* __restrict__ hidden,
    const float* __restrict__ gbuf,
    const float* __restrict__ gn_w,
    const float* __restrict__ gn_b,
    float* __restrict__ Zloc,
    float* __restrict__ Gbuf,
    unsigned short* __restrict__ act,
    float* __restrict__ hid_out,
    int real_only)
{
    cg::grid_group grid = cg::this_grid();
    const int blk = blockIdx.x;
    const int c  = blk & 7;
    const int bh = blk >> 3;
    const int b = bh >> 3, h = bh & 7;
    const int t = threadIdx.x;
    const int l0 = c * 64;

    __shared__ unsigned short pQr[4096], pQi[4096];   // Q~ [l][i] — persists
    __shared__ unsigned short pKr[4096], pKi[4096];   // K~ [m][i]; later Zin [v][i]
    __shared__ unsigned short pKtr[4096], pKti[4096]; // K~T [i][m]
    __shared__ unsigned short pVtr[4096], pVti[4096]; // V^T [v][m]
    __shared__ unsigned short pPr[4096], pPi[4096];   // masked P [l][m]
    __shared__ float sW[64][4];
    __shared__ float sTh[64];
    __shared__ float sG[8][2];

    // --- Phase 1: lambda cumprod scan (wave 0) + p_angle stash ---
    if (t < 64) {
        sTh[t] = p_angle[h * DQK_ + t];
        const float th0 = p_angle[h * DQK_];
        const float a = a_pad[((size_t)(b * L_) + l0 + t) * 128 + h];
        float sa, ca; __sincosf(a * th0, &sa, &ca);
        const float em = expf(-th0), ep = expf(th0);
        float lr = em * ca, li = em * sa;      // lambda
        float ir = ep * ca, ii = -ep * sa;     // 1/lambda
#pragma unroll
        for (int off = 1; off < 64; off <<= 1) {
            const float plr = __shfl_up(lr, off);
            const float pli = __shfl_up(li, off);
            const float pir = __shfl_up(ir, off);
            const float pii = __shfl_up(ii, off);
            if (t >= off) {
                float nr = lr * plr - li * pli;
                float ni = lr * pli + li * plr;
                lr = nr; li = ni;
                nr = ir * pir - ii * pii;
                ni = ir * pii + ii * pir;
                ir = nr; ii = ni;
            }
        }
        sW[t][0] = lr; sW[t][1] = li; sW[t][2] = ir; sW[t][3] = ii;
        if (t == 63) {
            Gbuf[(bh * 8 + c) * 2 + 0] = lr;
            Gbuf[(bh * 8 + c) * 2 + 1] = li;
        }
    }
    __syncthreads();

    // --- load planes: thread t owns (row = t>>2, 16-col segment cs = t&3) ---
    const int row = t >> 2, cs = t & 3;
    {
        const float wr = sW[row][0], wi = sW[row][1];
        const float xr = sW[row][2], xi = sW[row][3];
        const float lf = (float)(l0 + row);
        unsigned short qr16[16], qi16[16], kr16[16], ki16[16];
        const unsigned short* qg = qk_bf +
            (size_t)(b * L_ + l0 + row) * 2048 + h * 256 + cs * 64;
#pragma unroll
        for (int j = 0; j < 16; ++j) {
            const ushort4 qu = *(const ushort4*)(qg + j * 4);
            const float qre = bf2f(qu.x), qim = bf2f(qu.y);
            const float kre = bf2f(qu.z), kim = bf2f(qu.w);
            float sn, cn; __sincosf(sTh[cs * 16 + j] * lf, &sn, &cn);
            const float fqr = cn * wr - sn * wi, fqi = cn * wi + sn * wr;
            const float fkr = cn * xr + sn * xi, fki = cn * xi - sn * xr;
            qr16[j] = f2bf(qre * fqr - qim * fqi);
            qi16[j] = f2bf(qre * fqi + qim * fqr);
            const float kr = kre * fkr - kim * fki;
            const float ki = kre * fki + kim * fkr;
            kr16[j] = f2bf(kr); ki16[j] = f2bf(ki);
            const int i = cs * 16 + j;      // transposed K writes [i][m=row]
            const int ob = swoff(i, 2 * row);
            *(unsigned short*)((char*)pKtr + ob) = kr16[j];
            *(unsigned short*)((char*)pKti + ob) = ki16[j];
        }
        const int kb0 = 32 * cs;
        short8 s0, s1;
#pragma unroll
        for (int j = 0; j < 8; ++j) { s0[j] = (short)qr16[j]; s1[j] = (short)qr16[8 + j]; }
        *(short8*)((char*)pQr + swoff(row, kb0))      = s0;
        *(short8*)((char*)pQr + swoff(row, kb0 + 16)) = s1;
#pragma unroll
        for (int j = 0; j < 8; ++j) { s0[j] = (short)qi16[j]; s1[j] = (short)qi16[8 + j]; }
        *(short8*)((char*)pQi + swoff(row, kb0))      = s0;
        *(short8*)((char*)pQi + swoff(row, kb0 + 16)) = s1;
#pragma unroll
        for (int j = 0; j < 8; ++j) { s0[j] = (short)kr16[j]; s1[j] = (short)kr16[8 + j]; }
        *(short8*)((char*)pKr + swoff(row, kb0))      = s0;
        *(short8*)((char*)pKr + swoff(row, kb0 + 16)) = s1;
#pragma unroll
        for (int j = 0; j < 8; ++j) { s0[j] = (short)ki16[j]; s1[j] = (short)ki16[8 + j]; }
        *(short8*)((char*)pKi + swoff(row, kb0))      = s0;
        *(short8*)((char*)pKi + swoff(row, kb0 + 16)) = s1;

        const unsigned short* vg = v_bf +
            (size_t)(b * L_ + l0 + row) * 1024 + h * 128 + cs * 32;
#pragma unroll
        for (int j = 0; j < 16; ++j) {
            const ushort2 vv = *(const ushort2*)(vg + j * 2);
            const int v = cs * 16 + j;      // transposed V writes [v][m=row]
            const int ob = swoff(v, 2 * row);
            *(unsigned short*)((char*)pVtr + ob) = vv.x;
            *(unsigned short*)((char*)pVti + ob) = vv.y;
        }
    }
    __syncthreads();

    // --- P = Q~ K~^T (wave w owns l-strip w) ---
    const int w = t >> 6, lane = t & 63;
    const int fr = lane & 15, fq = lane >> 4;
    {
        short8 aQr0 = frag(pQr, w, 0, lane), aQr1 = frag(pQr, w, 1, lane);
        short8 aQi0 = frag(pQi, w, 0, lane), aQi1 = frag(pQi, w, 1, lane);
        f32x4 Pr[4], Pi[4];
#pragma unroll
        for (int tm = 0; tm < 4; ++tm) {
            short8 bKr0 = frag(pKr, tm, 0, lane), bKr1 = frag(pKr, tm, 1, lane);
            short8 bKi0 = frag(pKi, tm, 0, lane), bKi1 = frag(pKi, tm, 1, lane);
            f32x4 tmp = {};
            tmp = mm16(aQi0, bKi0, tmp); tmp = mm16(aQi1, bKi1, tmp);
            tmp = -tmp;
            tmp = mm16(aQr0, bKr0, tmp); tmp = mm16(aQr1, bKr1, tmp);
            Pr[tm] = tmp;
            f32x4 t2 = {};
            t2 = mm16(aQr0, bKi0, t2); t2 = mm16(aQr1, bKi1, t2);
            t2 = mm16(aQi0, bKr0, t2); t2 = mm16(aQi1, bKr1, t2);
            Pi[tm] = t2;
        }
        // mask (keep m<=l), write P into pPr/pPi (wave-own rows: no barrier)
#pragma unroll
        for (int tm = 0; tm < 4; ++tm) {
            const int m = tm * 16 + fr;
#pragma unroll
            for (int r = 0; r < 4; ++r) {
                const int l = w * 16 + fq * 4 + r;
                const int ob = swoff(l, 2 * m);
                const float prv = (m <= l) ? Pr[tm][r] : 0.f;
                const float piv = (m <= l) ? Pi[tm][r] : 0.f;
                *(unsigned short*)((char*)pPr + ob) = f2bf(prv);
                *(unsigned short*)((char*)pPi + ob) = f2bf(piv);
            }
        }
    }

    // --- H = P V (into registers) and Z = K~^T V -> Zloc ---
    float hreg[4][4][2];
    {
        short8 aPr0 = frag(pPr, w, 0, lane), aPr1 = frag(pPr, w, 1, lane);
        short8 aPi0 = frag(pPi, w, 0, lane), aPi1 = frag(pPi, w, 1, lane);
        short8 aKt_r0 = frag(pKtr, w, 0, lane), aKt_r1 = frag(pKtr, w, 1, lane);
        short8 aKt_i0 = frag(pKti, w, 0, lane), aKt_i1 = frag(pKti, w, 1, lane);
        const float Gr = sW[63][0], Gi = sW[63][1];
#pragma unroll
        for (int tv = 0; tv < 4; ++tv) {
            short8 bVr0 = frag(pVtr, tv, 0, lane), bVr1 = frag(pVtr, tv, 1, lane);
            short8 bVi0 = frag(pVti, tv, 0, lane), bVi1 = frag(pVti, tv, 1, lane);
            f32x4 hr = {};
            hr = mm16(aPi0, bVi0, hr); hr = mm16(aPi1, bVi1, hr);
            hr = -hr;
            hr = mm16(aPr0, bVr0, hr); hr = mm16(aPr1, bVr1, hr);
            f32x4 hi = {};
            hi = mm16(aPr0, bVi0, hi); hi = mm16(aPr1, bVi1, hi);
            hi = mm16(aPi0, bVr0, hi); hi = mm16(aPi1, bVr1, hi);
            f32x4 zr = {};
            zr = mm16(aKt_i0, bVi0, zr); zr = mm16(aKt_i1, bVi1, zr);
            zr = -zr;
            zr = mm16(aKt_r0, bVr0, zr); zr = mm16(aKt_r1, bVr1, zr);
            f32x4 zi = {};
            zi = mm16(aKt_r0, bVi0, zi); zi = mm16(aKt_r1, bVi1, zi);
            zi = mm16(aKt_i0, bVr0, zi); zi = mm16(aKt_i1, bVr1, zi);
#pragma unroll
            for (int r = 0; r < 4; ++r) {
                const int lrow = w * 16 + fq * 4 + r;    // i for Z
                const int v = tv * 16 + fr;
                hreg[tv][r][0] = hr[r];
                hreg[tv][r][1] = hi[r];
                float* zp = Zloc + (((size_t)(bh * 8 + c) * 4096) + lrow * 64 + v) * 2;
                zp[0] = Gr * zr[r] - Gi * zi[r];
                zp[1] = Gr * zi[r] + Gi * zr[r];
            }
        }
    }

    __threadfence();
    grid.sync();

    // --- Phase 2: redundant prefix scan -> own Zin planes (pKr/pKi) ---
    if (t < 8) {
        sG[t][0] = Gbuf[(bh * 8 + t) * 2 + 0];
        sG[t][1] = Gbuf[(bh * 8 + t) * 2 + 1];
    }
    __syncthreads();

#pragma unroll
    for (int k = 0; k < 16; ++k) {
        const int e = k * 256 + t;           // 0..4095, coalesced
        const int i = e >> 6, v = e & 63;
        const float th = sTh[i];
        float sn, cn; __sincosf(th, &sn, &cn);
        const float2 h0 = *(const float2*)(hidden + ((size_t)bh * 4096 + e) * 2);
        float zr = h0.x * cn - h0.y * sn;
        float zi = h0.x * sn + h0.y * cn;
        for (int j = 0; j < c; ++j) {
            const float gr = sG[j][0], gi = sG[j][1];
            const float2 zl = *(const float2*)(Zloc + ((size_t)(bh * 8 + j) * 4096 + e) * 2);
            const float nr = gr * zr - gi * zi + zl.x;
            const float ni = gr * zi + gi * zr + zl.y;
            zr = nr; zi = ni;
        }
        const int ob = swoff(v, 2 * i);
        *(unsigned short*)((char*)pKr + ob) = f2bf(zr);
        *(unsigned short*)((char*)pKi + ob) = f2bf(zi);
        if (c == 7) {
            const float gr = sG[7][0], gi = sG[7][1];
            const float2 zl = *(const float2*)(Zloc + ((size_t)(bh * 8 + 7) * 4096 + e) * 2);
            const float fr2 = gr * zr - gi * zi + zl.x;
            const float fi2 = gr * zi + gi * zr + zl.y;
            float s2, c2v; __sincosf(th * (float)(L_ - 1), &s2, &c2v);
            const float outr = fr2 * c2v - fi2 * s2;
            const float outi = fr2 * s2 + fi2 * c2v;
            if (real_only) {
                hid_out[(size_t)bh * 4096 + e] = outr;
            } else {
                hid_out[((size_t)bh * 4096 + e) * 2 + 0] = outr;
                hid_out[((size_t)bh * 4096 + e) * 2 + 1] = outi;
            }
        }
    }
    __syncthreads();

    // --- Phase 3: hreg += Q~ . Zin (Q~ planes still resident) ---
#pragma unroll
    for (int tv = 0; tv < 4; ++tv) {
        short8 aQr0 = frag(pQr, w, 0, lane), aQr1 = frag(pQr, w, 1, lane);
        short8 aQi0 = frag(pQi, w, 0, lane), aQi1 = frag(pQi, w, 1, lane);
        short8 bZr0 = frag(pKr, tv, 0, lane), bZr1 = frag(pKr, tv, 1, lane);
        short8 bZi0 = frag(pKi, tv, 0, lane), bZi1 = frag(pKi, tv, 1, lane);
        f32x4 hr = {};
        hr = mm16(aQi0, bZi0, hr); hr = mm16(aQi1, bZi1, hr);
        hr = -hr;
        hr = mm16(aQr0, bZr0, hr); hr = mm16(aQr1, bZr1, hr);
        f32x4 hi = {};
        hi = mm16(aQr0, bZi0, hi); hi = mm16(aQr1, bZi1, hi);
        hi = mm16(aQi0, bZr0, hi); hi = mm16(aQi1, bZr1, hi);
#pragma unroll
        for (int r = 0; r < 4; ++r) {
            hreg[tv][r][0] += hr[r];
            hreg[tv][r][1] += hi[r];
        }
    }

    // --- per-row GroupNorm stats (reduce over fr lanes within fq group) ---
    const float gw = gn_w[h], gbn = gn_b[h];
    float mean4[4], scl4[4];
#pragma unroll
    for (int r = 0; r < 4; ++r) {
        float s = 0.f, q = 0.f;
#pragma unroll
        for (int tv = 0; tv < 4; ++tv) {
            s += hreg[tv][r][0] + hreg[tv][r][1];
            q += hreg[tv][r][0] * hreg[tv][r][0] + hreg[tv][r][1] * hreg[tv][r][1];
        }
#pragma unroll
        for (int off = 1; off < 16; off <<= 1) {
            s += __shfl_xor(s, off);
            q += __shfl_xor(q, off);
        }
        const float m = s * (1.f / 128.f);
        const float var = q * (1.f / 128.f) - m * m;
        mean4[r] = m;
        scl4[r] = rsqrtf(var + EPS_) * gw;
    }

    // --- gate + write act (bf16) ---
#pragma unroll
    for (int tv = 0; tv < 4; ++tv) {
#pragma unroll
        for (int r = 0; r < 4; ++r) {
            const int l = w * 16 + fq * 4 + r;
            const int v = tv * 16 + fr;
            const size_t base = (size_t)(b * L_ + l0 + l) * 1024 + h * 128 + v * 2;
            const float2 gv = *(const float2*)(gbuf + base);
            const float hn0 = (hreg[tv][r][0] - mean4[r]) * scl4[r] + gbn;
            const float hn1 = (hreg[tv][r][1] - mean4[r]) * scl4[r] + gbn;
            const float a0 = hn0 * gv.x / (1.f + expf(-gv.x));
            const float a1 = hn1 * gv.y / (1.f + expf(-gv.y));
            ushort2 o; o.x = f2bf(a0); o.y = f2bf(a1);
            *(ushort2*)(act + base) = o;
        }
    }
}

// ---------------------------------------------------------------------------
// Launch
// ---------------------------------------------------------------------------
extern "C" void kernel_launch(void* const* d_in, const int* in_sizes, int n_in,
                              void* d_out, int out_size, void* d_ws, size_t ws_size,
                              hipStream_t stream)
{
    (void)in_sizes; (void)n_in; (void)ws_size;
    const float* x       = (const float*)d_in[0];
    const float* hidden  = (const float*)d_in[1];
    const float* w_qk    = (const float*)d_in[2];
    const float* b_qk    = (const float*)d_in[3];
    const float* w_v     = (const float*)d_in[4];
    const float* b_v     = (const float*)d_in[5];
    const float* w_g     = (const float*)d_in[6];
    const float* b_g     = (const float*)d_in[7];
    const float* w_a     = (const float*)d_in[8];
    const float* b_a     = (const float*)d_in[9];
    const float* w_y     = (const float*)d_in[10];
    const float* b_y     = (const float*)d_in[11];
    const float* gn_w    = (const float*)d_in[12];
    const float* gn_b    = (const float*)d_in[13];
    const float* p_angle = (const float*)d_in[14];

    float* y_out   = (float*)d_out;
    float* hid_out = (float*)d_out + (size_t)M_ * DIM_;
    const int hid_elems = out_size - M_ * DIM_;
    int real_only = (hid_elems == B_ * H_ * DQK_ * DV_) ? 1 : 0;

    // ---- flat workspace layout ----
    unsigned short* xb     = (unsigned short*)d_ws;            // [2048][1024]
    unsigned short* wall   = xb   + (size_t)2048 * 1024;       // [4224][1024]
    unsigned short* wyb    = wall + (size_t)4224 * 1024;       // [1024][1024]
    unsigned short* bqk    = wyb  + (size_t)1024 * 1024;       // [2048][2048] bf16
    unsigned short* bv     = bqk  + (size_t)2048 * 2048;       // [2048][1024] bf16
    unsigned short* actb   = bv   + (size_t)2048 * 1024;       // [2048][1024] bf16
    float* bg     = (float*)(actb + (size_t)2048 * 1024);      // [2048][1024]
    float* ba_pad = bg     + (size_t)2048 * 1024;              // [2048][128]
    float* babias = ba_pad + (size_t)2048 * 128;               // [128]
    float* bufG   = babias + 128;                              // [32][8][2]
    float* bufZ   = bufG   + 512;                              // [256][4096][2]

    cast_all<<<7177, 256, 0, stream>>>(x, w_qk, w_v, w_g, w_y, w_a, b_a,
                                       xb, wall, wyb, babias);

    // fused qk|v|g|a projection: N = 4224 (4096 + 128 pad tile), 8 waves/block
    gemm_proj<<<dim3(33, 16), 512, 0, stream>>>(
        xb, wall, b_qk, b_v, b_g, babias,
        bqk, bv, bg, ba_pad,
        2048, 3072, 4096,
        2048, 1024, 1024, 128,
        1, 1, 0, 0,
        M_, 4224, DIM_);

    {
        const unsigned short* a0 = bqk;
        const unsigned short* a1 = bv;
        const float* a2 = ba_pad;
        const float* a3 = p_angle;
        const float* a4 = hidden;
        const float* a5 = bg;
        const float* a6 = gn_w;
        const float* a7 = gn_b;
        float* a8 = bufZ;
        float* a9 = bufG;
        unsigned short* a10 = actb;
        float* a11 = hid_out;
        void* args[] = { &a0, &a1, &a2, &a3, &a4, &a5, &a6, &a7,
                         &a8, &a9, &a10, &a11, &real_only };
        hipLaunchCooperativeKernel((void*)fused_chunks, dim3(B_ * H_ * 8),
                                   dim3(256), args, 0, stream);
    }

    gemm_y<<<dim3(16, 32), 256, 0, stream>>>(
        actb, wyb, b_y, y_out, M_, DIM_, DIM_);
}

// Round 12
// 89.751 us; speedup vs baseline: 2.1142x; 2.1142x over previous
//
#include <hip/hip_runtime.h>
#include <cstdint>
#include <cstddef>

// Problem constants
#define B_   4
#define L_   512
#define DIM_ 1024
#define H_   8
#define DQK_ 64
#define DV_  64
#define M_   (B_ * L_)          // 2048 rows
#define EPS_ 1e-5f

typedef __attribute__((ext_vector_type(8))) short short8;
typedef __attribute__((ext_vector_type(4))) float f32x4;

// ---------------------------------------------------------------------------
// bf16 helpers
// ---------------------------------------------------------------------------
__device__ __forceinline__ unsigned short f2bf(float f) {
    uint32_t u = __float_as_uint(f);
    u += 0x7FFFu + ((u >> 16) & 1u);
    return (unsigned short)(u >> 16);
}
__device__ __forceinline__ float bf2f(unsigned short u) {
    return __uint_as_float((uint32_t)u << 16);
}

__device__ __forceinline__ f32x4 mm16(short8 a, short8 b, f32x4 c) {
    return __builtin_amdgcn_mfma_f32_16x16x32_bf16(a, b, c, 0, 0, 0);
}

// 64x64 bf16 plane with XOR swizzle: element (r,c) at byte r*128 + ((2c)^((r&7)<<4))
__device__ __forceinline__ int swoff(int r, int kb) {
    return r * 128 + (kb ^ ((r & 7) << 4));
}
__device__ __forceinline__ short8 frag(const unsigned short* p, int strip, int ks, int lane) {
    const int fr = lane & 15, fq = lane >> 4;
    const int r = strip * 16 + fr;
    return *(const short8*)((const char*)p + swoff(r, ks * 64 + fq * 16));
}

// ---------------------------------------------------------------------------
// Fused cast: x, w_qk|w_v|w_g|w_a -> wall, w_y -> bf16; b_a -> padded bias.
// ---------------------------------------------------------------------------
__global__ __launch_bounds__(256) void cast_all(
    const float* __restrict__ x, const float* __restrict__ wqk,
    const float* __restrict__ wv, const float* __restrict__ wg,
    const float* __restrict__ wy, const float* __restrict__ wa,
    const float* __restrict__ ba,
    unsigned short* __restrict__ xb, unsigned short* __restrict__ wall,
    unsigned short* __restrict__ wyb, float* __restrict__ babias)
{
    const int blk = blockIdx.x;
    if (blk == 7176) {
        if (threadIdx.x < 128)
            babias[threadIdx.x] = (threadIdx.x < 8) ? ba[threadIdx.x] : 0.f;
        return;
    }
    const float* src; unsigned short* dst; int base;
    if      (blk < 2048) { src = x;   dst = xb;                  base = blk; }
    else if (blk < 4096) { src = wqk; dst = wall;                base = blk - 2048; }
    else if (blk < 5120) { src = wv;  dst = wall + 2048 * 1024;  base = blk - 4096; }
    else if (blk < 6144) { src = wg;  dst = wall + 3072 * 1024;  base = blk - 5120; }
    else if (blk < 7168) { src = wy;  dst = wyb;                 base = blk - 6144; }
    else                 { src = wa;  dst = wall + 4096 * 1024;  base = blk - 7168; }
    const int i = base * 256 + threadIdx.x;
    const float4 v = ((const float4*)src)[i];
    ushort4 o;
    o.x = f2bf(v.x); o.y = f2bf(v.y); o.z = f2bf(v.z); o.w = f2bf(v.w);
    ((ushort4*)dst)[i] = o;
}

// ---------------------------------------------------------------------------
// bf16 MFMA GEMM: 128x128 tile, BK=32, 512 threads / 8 waves (2 row x 4 col).
// Each wave: 64x32 output, acc[4][2]. 4-range split epilogue, per-range dtype.
// ---------------------------------------------------------------------------
__device__ __forceinline__ void gload16(const void* g, void* l) {
    __builtin_amdgcn_global_load_lds(
        (const __attribute__((address_space(1))) unsigned int*)g,
        (__attribute__((address_space(3))) unsigned int*)l, 16, 0, 0);
}

__global__ __launch_bounds__(512) void gemm_proj(
    const unsigned short* __restrict__ A, const unsigned short* __restrict__ W,
    const float* __restrict__ bias0, const float* __restrict__ bias1,
    const float* __restrict__ bias2, const float* __restrict__ bias3,
    void* __restrict__ C0, void* __restrict__ C1,
    void* __restrict__ C2, void* __restrict__ C3,
    int n1, int n2, int n3,
    int ld0, int ld1, int ld2, int ld3,
    int bf0, int bf1, int bf2, int bf3,
    int M, int N, int K)
{
    __shared__ unsigned short sA[128 * 32];
    __shared__ unsigned short sB[128 * 32];

    const int t    = threadIdx.x;
    const int lane = t & 63;
    const int wv   = t >> 6;          // 0..7
    const int bm   = blockIdx.y * 128;
    const int bn   = blockIdx.x * 128;
    const int wr   = wv >> 2;         // 0..1  (64-row half)
    const int wc   = wv & 3;          // 0..3  (32-col quarter)
    const int fr   = lane & 15;
    const int fq   = lane >> 4;
    const int srow = lane >> 2;
    const int ske  = (lane & 3) * 8;

    f32x4 acc[4][2] = {};

    for (int k0 = 0; k0 < K; k0 += 32) {
        // wave wv stages A rows [wv*16, wv*16+16) and same B rows: 1 gload each
        gload16(A + (size_t)(bm + wv * 16 + srow) * K + k0 + ske,
                (char*)sA + wv * 1024);
        gload16(W + (size_t)(bn + wv * 16 + srow) * K + k0 + ske,
                (char*)sB + wv * 1024);
        __syncthreads();

        short8 af[4], bf[2];
#pragma unroll
        for (int mi = 0; mi < 4; ++mi)
            af[mi] = *(const short8*)&sA[(wr * 64 + mi * 16 + fr) * 32 + fq * 8];
#pragma unroll
        for (int ni = 0; ni < 2; ++ni)
            bf[ni] = *(const short8*)&sB[(wc * 32 + ni * 16 + fr) * 32 + fq * 8];
#pragma unroll
        for (int mi = 0; mi < 4; ++mi)
#pragma unroll
            for (int ni = 0; ni < 2; ++ni)
                acc[mi][ni] = mm16(af[mi], bf[ni], acc[mi][ni]);
        __syncthreads();
    }

    void* Cb; const float* bb; int coff, ldc, isbf;
    if      (bn < n1) { Cb = C0; bb = bias0; coff = 0;  ldc = ld0; isbf = bf0; }
    else if (bn < n2) { Cb = C1; bb = bias1; coff = n1; ldc = ld1; isbf = bf1; }
    else if (bn < n3) { Cb = C2; bb = bias2; coff = n2; ldc = ld2; isbf = bf2; }
    else              { Cb = C3; bb = bias3; coff = n3; ldc = ld3; isbf = bf3; }

#pragma unroll
    for (int mi = 0; mi < 4; ++mi)
#pragma unroll
        for (int ni = 0; ni < 2; ++ni) {
            const int col = bn + wc * 32 + ni * 16 + fr - coff;
            const float bv = bb[col];
#pragma unroll
            for (int r = 0; r < 4; ++r) {
                const int row = bm + wr * 64 + mi * 16 + fq * 4 + r;
                const float val = acc[mi][ni][r] + bv;
                if (isbf)
                    ((unsigned short*)Cb)[(size_t)row * ldc + col] = f2bf(val);
                else
                    ((float*)Cb)[(size_t)row * ldc + col] = val;
            }
        }
}

// ---------------------------------------------------------------------------
// y GEMM: 64x64 tile, 4 waves (each 32x32) -> grid (16,32) = 512 blocks.
// ---------------------------------------------------------------------------
__global__ __launch_bounds__(256) void gemm_y(
    const unsigned short* __restrict__ A, const unsigned short* __restrict__ W,
    const float* __restrict__ bias, float* __restrict__ C,
    int M, int N, int K)
{
    __shared__ unsigned short sA[64 * 32];
    __shared__ unsigned short sB[64 * 32];

    const int t    = threadIdx.x;
    const int lane = t & 63;
    const int wv   = t >> 6;          // 0..3
    const int bm   = blockIdx.y * 64;
    const int bn   = blockIdx.x * 64;
    const int wr   = wv >> 1;         // 0..1
    const int wc   = wv & 1;          // 0..1
    const int fr   = lane & 15;
    const int fq   = lane >> 4;
    const int srow = lane >> 2;
    const int ske  = (lane & 3) * 8;

    f32x4 acc[2][2] = {};

    for (int k0 = 0; k0 < K; k0 += 32) {
        gload16(A + (size_t)(bm + wv * 16 + srow) * K + k0 + ske,
                (char*)sA + wv * 1024);
        gload16(W + (size_t)(bn + wv * 16 + srow) * K + k0 + ske,
                (char*)sB + wv * 1024);
        __syncthreads();

        short8 af[2], bf[2];
#pragma unroll
        for (int mi = 0; mi < 2; ++mi)
            af[mi] = *(const short8*)&sA[(wr * 32 + mi * 16 + fr) * 32 + fq * 8];
#pragma unroll
        for (int ni = 0; ni < 2; ++ni)
            bf[ni] = *(const short8*)&sB[(wc * 32 + ni * 16 + fr) * 32 + fq * 8];
#pragma unroll
        for (int mi = 0; mi < 2; ++mi)
#pragma unroll
            for (int ni = 0; ni < 2; ++ni)
                acc[mi][ni] = mm16(af[mi], bf[ni], acc[mi][ni]);
        __syncthreads();
    }

#pragma unroll
    for (int mi = 0; mi < 2; ++mi)
#pragma unroll
        for (int ni = 0; ni < 2; ++ni) {
            const int col = bn + wc * 32 + ni * 16 + fr;
            const float bv = bias[col];
#pragma unroll
            for (int r = 0; r < 4; ++r) {
                const int row = bm + wr * 32 + mi * 16 + fq * 4 + r;
                C[(size_t)row * N + col] = acc[mi][ni][r] + bv;
            }
        }
}

// ---------------------------------------------------------------------------
// chunkA: one block per (b,h,chunk), 256 threads / 4 waves.
// qk, v inputs are bf16. Phase folded into load transform.
// P = Q~K~^T (masked), H = P V, Z = K~^T V via mfma_16x16x32_bf16.
// ---------------------------------------------------------------------------
__global__ __launch_bounds__(256) void chunkA_mfma(
    const unsigned short* __restrict__ qk_bf, const unsigned short* __restrict__ v_bf,
    const float* __restrict__ a_pad, const float* __restrict__ p_angle,
    float* __restrict__ h_pre, float* __restrict__ Zloc,
    float* __restrict__ Gbuf, float* __restrict__ Wbuf)
{
    const int blk = blockIdx.x;
    const int c  = blk & 7;
    const int bh = blk >> 3;
    const int b = bh >> 3, h = bh & 7;
    const int t = threadIdx.x;
    const int l0 = c * 64;

    __shared__ unsigned short pQr[4096], pQi[4096];   // later reused as Pr, Pi
    __shared__ unsigned short pKr[4096], pKi[4096];   // [m][i]
    __shared__ unsigned short pKtr[4096], pKti[4096]; // [i][m]
    __shared__ unsigned short pVtr[4096], pVti[4096]; // [v][m]
    __shared__ float sW[64][4];
    __shared__ float sTh[64];

    // --- lambda cumprod scan (wave 0) + p_angle stash ---
    if (t < 64) {
        sTh[t] = p_angle[h * DQK_ + t];
        const float th0 = p_angle[h * DQK_];
        const float a = a_pad[((size_t)(b * L_) + l0 + t) * 128 + h];
        float sa, ca; __sincosf(a * th0, &sa, &ca);
        const float em = expf(-th0), ep = expf(th0);
        float lr = em * ca, li = em * sa;      // lambda
        float ir = ep * ca, ii = -ep * sa;     // 1/lambda
#pragma unroll
        for (int off = 1; off < 64; off <<= 1) {
            const float plr = __shfl_up(lr, off);
            const float pli = __shfl_up(li, off);
            const float pir = __shfl_up(ir, off);
            const float pii = __shfl_up(ii, off);
            if (t >= off) {
                float nr = lr * plr - li * pli;
                float ni = lr * pli + li * plr;
                lr = nr; li = ni;
                nr = ir * pir - ii * pii;
                ni = ir * pii + ii * pir;
                ir = nr; ii = ni;
            }
        }
        sW[t][0] = lr; sW[t][1] = li; sW[t][2] = ir; sW[t][3] = ii;
        Wbuf[((size_t)bh * L_ + l0 + t) * 2 + 0] = lr;
        Wbuf[((size_t)bh * L_ + l0 + t) * 2 + 1] = li;
        if (t == 63) {
            Gbuf[(bh * 8 + c) * 2 + 0] = lr;
            Gbuf[(bh * 8 + c) * 2 + 1] = li;
        }
    }
    __syncthreads();

    // --- load planes: thread t owns (row = t>>2, 16-col segment cs = t&3) ---
    const int row = t >> 2, cs = t & 3;
    {
        const float wr = sW[row][0], wi = sW[row][1];
        const float xr = sW[row][2], xi = sW[row][3];
        const float lf = (float)(l0 + row);
        unsigned short qr16[16], qi16[16], kr16[16], ki16[16];
        const unsigned short* qg = qk_bf +
            (size_t)(b * L_ + l0 + row) * 2048 + h * 256 + cs * 64;
#pragma unroll
        for (int j = 0; j < 16; ++j) {
            const ushort4 qu = *(const ushort4*)(qg + j * 4);
            const float qre = bf2f(qu.x), qim = bf2f(qu.y);
            const float kre = bf2f(qu.z), kim = bf2f(qu.w);
            float sn, cn; __sincosf(sTh[cs * 16 + j] * lf, &sn, &cn);
            // q~ = q * e^{+i l th} * W ;  k~ = k * e^{-i l th} * invW
            const float fqr = cn * wr - sn * wi, fqi = cn * wi + sn * wr;
            const float fkr = cn * xr + sn * xi, fki = cn * xi - sn * xr;
            qr16[j] = f2bf(qre * fqr - qim * fqi);
            qi16[j] = f2bf(qre * fqi + qim * fqr);
            const float kr = kre * fkr - kim * fki;
            const float ki = kre * fki + kim * fkr;
            kr16[j] = f2bf(kr); ki16[j] = f2bf(ki);
            const int i = cs * 16 + j;      // transposed K writes [i][m=row]
            const int ob = swoff(i, 2 * row);
            *(unsigned short*)((char*)pKtr + ob) = kr16[j];
            *(unsigned short*)((char*)pKti + ob) = ki16[j];
        }
        const int kb0 = 32 * cs;
        short8 s0, s1;
#pragma unroll
        for (int j = 0; j < 8; ++j) { s0[j] = (short)qr16[j]; s1[j] = (short)qr16[8 + j]; }
        *(short8*)((char*)pQr + swoff(row, kb0))      = s0;
        *(short8*)((char*)pQr + swoff(row, kb0 + 16)) = s1;
#pragma unroll
        for (int j = 0; j < 8; ++j) { s0[j] = (short)qi16[j]; s1[j] = (short)qi16[8 + j]; }
        *(short8*)((char*)pQi + swoff(row, kb0))      = s0;
        *(short8*)((char*)pQi + swoff(row, kb0 + 16)) = s1;
#pragma unroll
        for (int j = 0; j < 8; ++j) { s0[j] = (short)kr16[j]; s1[j] = (short)kr16[8 + j]; }
        *(short8*)((char*)pKr + swoff(row, kb0))      = s0;
        *(short8*)((char*)pKr + swoff(row, kb0 + 16)) = s1;
#pragma unroll
        for (int j = 0; j < 8; ++j) { s0[j] = (short)ki16[j]; s1[j] = (short)ki16[8 + j]; }
        *(short8*)((char*)pKi + swoff(row, kb0))      = s0;
        *(short8*)((char*)pKi + swoff(row, kb0 + 16)) = s1;

        const unsigned short* vg = v_bf +
            (size_t)(b * L_ + l0 + row) * 1024 + h * 128 + cs * 32;
#pragma unroll
        for (int j = 0; j < 16; ++j) {
            const ushort2 vv = *(const ushort2*)(vg + j * 2);
            const int v = cs * 16 + j;      // transposed V writes [v][m=row]
            const int ob = swoff(v, 2 * row);
            *(unsigned short*)((char*)pVtr + ob) = vv.x;
            *(unsigned short*)((char*)pVti + ob) = vv.y;
        }
    }
    __syncthreads();

    // --- P = Q~ K~^T (wave w owns l-strip w) ---
    const int w = t >> 6, lane = t & 63;
    const int fr = lane & 15, fq = lane >> 4;
    short8 aQr0 = frag(pQr, w, 0, lane), aQr1 = frag(pQr, w, 1, lane);
    short8 aQi0 = frag(pQi, w, 0, lane), aQi1 = frag(pQi, w, 1, lane);
    f32x4 Pr[4], Pi[4];
#pragma unroll
    for (int tm = 0; tm < 4; ++tm) {
        short8 bKr0 = frag(pKr, tm, 0, lane), bKr1 = frag(pKr, tm, 1, lane);
        short8 bKi0 = frag(pKi, tm, 0, lane), bKi1 = frag(pKi, tm, 1, lane);
        f32x4 tmp = {};
        tmp = mm16(aQi0, bKi0, tmp); tmp = mm16(aQi1, bKi1, tmp);
        tmp = -tmp;
        tmp = mm16(aQr0, bKr0, tmp); tmp = mm16(aQr1, bKr1, tmp);
        Pr[tm] = tmp;
        f32x4 t2 = {};
        t2 = mm16(aQr0, bKi0, t2); t2 = mm16(aQr1, bKi1, t2);
        t2 = mm16(aQi0, bKr0, t2); t2 = mm16(aQi1, bKr1, t2);
        Pi[tm] = t2;
    }
    // mask (keep m<=l) and write P into pQr/pQi (wave-own rows only: no barrier)
#pragma unroll
    for (int tm = 0; tm < 4; ++tm) {
        const int m = tm * 16 + fr;
#pragma unroll
        for (int r = 0; r < 4; ++r) {
            const int l = w * 16 + fq * 4 + r;
            const int ob = swoff(l, 2 * m);
            const float prv = (m <= l) ? Pr[tm][r] : 0.f;
            const float piv = (m <= l) ? Pi[tm][r] : 0.f;
            *(unsigned short*)((char*)pQr + ob) = f2bf(prv);
            *(unsigned short*)((char*)pQi + ob) = f2bf(piv);
        }
    }

    // --- H = P V and Z = K~^T V (shared V fragments) ---
    short8 aPr0 = frag(pQr, w, 0, lane), aPr1 = frag(pQr, w, 1, lane);
    short8 aPi0 = frag(pQi, w, 0, lane), aPi1 = frag(pQi, w, 1, lane);
    short8 aKt_r0 = frag(pKtr, w, 0, lane), aKt_r1 = frag(pKtr, w, 1, lane);
    short8 aKt_i0 = frag(pKti, w, 0, lane), aKt_i1 = frag(pKti, w, 1, lane);
    const float Gr = sW[63][0], Gi = sW[63][1];
#pragma unroll
    for (int tv = 0; tv < 4; ++tv) {
        short8 bVr0 = frag(pVtr, tv, 0, lane), bVr1 = frag(pVtr, tv, 1, lane);
        short8 bVi0 = frag(pVti, tv, 0, lane), bVi1 = frag(pVti, tv, 1, lane);
        f32x4 hr = {};
        hr = mm16(aPi0, bVi0, hr); hr = mm16(aPi1, bVi1, hr);
        hr = -hr;
        hr = mm16(aPr0, bVr0, hr); hr = mm16(aPr1, bVr1, hr);
        f32x4 hi = {};
        hi = mm16(aPr0, bVi0, hi); hi = mm16(aPr1, bVi1, hi);
        hi = mm16(aPi0, bVr0, hi); hi = mm16(aPi1, bVr1, hi);
        f32x4 zr = {};
        zr = mm16(aKt_i0, bVi0, zr); zr = mm16(aKt_i1, bVi1, zr);
        zr = -zr;
        zr = mm16(aKt_r0, bVr0, zr); zr = mm16(aKt_r1, bVr1, zr);
        f32x4 zi = {};
        zi = mm16(aKt_r0, bVi0, zi); zi = mm16(aKt_r1, bVi1, zi);
        zi = mm16(aKt_i0, bVr0, zi); zi = mm16(aKt_i1, bVr1, zi);
#pragma unroll
        for (int r = 0; r < 4; ++r) {
            const int lrow = w * 16 + fq * 4 + r;    // l for H, i for Z
            const int v = tv * 16 + fr;
            *(float2*)(h_pre + (((size_t)(b * L_ + l0 + lrow) * H_ + h) * 64 + v) * 2)
                = make_float2(hr[r], hi[r]);
            float* zp = Zloc + (((size_t)(bh * 8 + c) * 4096) + lrow * 64 + v) * 2;
            zp[0] = Gr * zr[r] - Gi * zi[r];
            zp[1] = Gr * zi[r] + Gi * zr[r];
        }
    }
}

// ---------------------------------------------------------------------------
// scanB: sequential over 8 chunks, parallel over entries. In-place Zloc->Zin.
// ---------------------------------------------------------------------------
__global__ __launch_bounds__(512) void scanB(
    float* __restrict__ Zbuf, const float* __restrict__ Gbuf,
    const float* __restrict__ hidden, const float* __restrict__ p_angle,
    float* __restrict__ hid_out, int real_only)
{
    const int bid = blockIdx.x;
    const int bh = bid >> 3, part = bid & 7;
    const int h = bh & 7;
    const int e = part * 512 + threadIdx.x;
    const int i = e >> 6;
    const float th = p_angle[h * 64 + i];
    float s, c; __sincosf(th, &s, &c);
    const float2 h0 = *(const float2*)(hidden + ((size_t)bh * 4096 + e) * 2);
    float zr = h0.x * c - h0.y * s;
    float zi = h0.x * s + h0.y * c;
#pragma unroll
    for (int ch = 0; ch < 8; ++ch) {
        float* zp = Zbuf + ((size_t)(bh * 8 + ch) * 4096 + e) * 2;
        const float zlr = zp[0], zli = zp[1];
        zp[0] = zr; zp[1] = zi;
        const float gr = Gbuf[(bh * 8 + ch) * 2], gi = Gbuf[(bh * 8 + ch) * 2 + 1];
        const float nr = gr * zr - gi * zi + zlr;
        const float ni = gr * zi + gi * zr + zli;
        zr = nr; zi = ni;
    }
    float s2, c2; __sincosf(th * (float)(L_ - 1), &s2, &c2);
    const float outr = zr * c2 - zi * s2;
    const float outi = zr * s2 + zi * c2;
    if (real_only) {
        hid_out[(size_t)bh * 4096 + e] = outr;
    } else {
        hid_out[((size_t)bh * 4096 + e) * 2 + 0] = outr;
        hid_out[((size_t)bh * 4096 + e) * 2 + 1] = outi;
    }
}

// ---------------------------------------------------------------------------
// chunkC_gn: h = h_intra + Q~.Zin, fused GroupNorm + SiLU gate -> act bf16.
// qk input is bf16.
// ---------------------------------------------------------------------------
__global__ __launch_bounds__(256) void chunkC_gn(
    const unsigned short* __restrict__ qk_bf, const float* __restrict__ Wbuf,
    const float* __restrict__ Zin, const float* __restrict__ p_angle,
    const float* __restrict__ h_intra, const float* __restrict__ gbuf,
    const float* __restrict__ gn_w, const float* __restrict__ gn_b,
    unsigned short* __restrict__ act)
{
    const int blk = blockIdx.x;
    const int c = blk & 7, bh = blk >> 3;
    const int b = bh >> 3, h = bh & 7;
    const int t = threadIdx.x;
    const int l0 = c * 64;

    __shared__ unsigned short pQr[4096], pQi[4096];   // [l][i]
    __shared__ unsigned short pZtr[4096], pZti[4096]; // [v][i]
    __shared__ float sTh[64];

    if (t < 64) sTh[t] = p_angle[h * 64 + t];
    __syncthreads();

    const int row = t >> 2, cs = t & 3;
    {
        const float wr = Wbuf[((size_t)bh * L_ + l0 + row) * 2];
        const float wi = Wbuf[((size_t)bh * L_ + l0 + row) * 2 + 1];
        const float lf = (float)(l0 + row);
        unsigned short qr16[16], qi16[16];
        const unsigned short* qg = qk_bf +
            (size_t)(b * L_ + l0 + row) * 2048 + h * 256 + cs * 64;
#pragma unroll
        for (int j = 0; j < 16; ++j) {
            const ushort4 qu = *(const ushort4*)(qg + j * 4);
            const float qre = bf2f(qu.x), qim = bf2f(qu.y);
            float sn, cn; __sincosf(sTh[cs * 16 + j] * lf, &sn, &cn);
            const float fqr = cn * wr - sn * wi, fqi = cn * wi + sn * wr;
            qr16[j] = f2bf(qre * fqr - qim * fqi);
            qi16[j] = f2bf(qre * fqi + qim * fqr);
        }
        const int kb0 = 32 * cs;
        short8 s0, s1;
#pragma unroll
        for (int j = 0; j < 8; ++j) { s0[j] = (short)qr16[j]; s1[j] = (short)qr16[8 + j]; }
        *(short8*)((char*)pQr + swoff(row, kb0))      = s0;
        *(short8*)((char*)pQr + swoff(row, kb0 + 16)) = s1;
#pragma unroll
        for (int j = 0; j < 8; ++j) { s0[j] = (short)qi16[j]; s1[j] = (short)qi16[8 + j]; }
        *(short8*)((char*)pQi + swoff(row, kb0))      = s0;
        *(short8*)((char*)pQi + swoff(row, kb0 + 16)) = s1;

        // Zin row i=row, v-seg: write transposed [v][i]
        const float2* zg = (const float2*)(Zin +
            ((size_t)(bh * 8 + c) * 4096 + row * 64 + cs * 16) * 2);
#pragma unroll
        for (int j = 0; j < 16; ++j) {
            const float2 z = zg[j];
            const int v = cs * 16 + j;
            const int ob = swoff(v, 2 * row);
            *(unsigned short*)((char*)pZtr + ob) = f2bf(z.x);
            *(unsigned short*)((char*)pZti + ob) = f2bf(z.y);
        }
    }
    __syncthreads();

    const int w = t >> 6, lane = t & 63;
    const int fr = lane & 15, fq = lane >> 4;
    short8 aQr0 = frag(pQr, w, 0, lane), aQr1 = frag(pQr, w, 1, lane);
    short8 aQi0 = frag(pQi, w, 0, lane), aQi1 = frag(pQi, w, 1, lane);

    float hreg[4][4][2];   // [tv][r][ri]
#pragma unroll
    for (int tv = 0; tv < 4; ++tv) {
        short8 bZr0 = frag(pZtr, tv, 0, lane), bZr1 = frag(pZtr, tv, 1, lane);
        short8 bZi0 = frag(pZti, tv, 0, lane), bZi1 = frag(pZti, tv, 1, lane);
        f32x4 hr = {};
        hr = mm16(aQi0, bZi0, hr); hr = mm16(aQi1, bZi1, hr);
        hr = -hr;
        hr = mm16(aQr0, bZr0, hr); hr = mm16(aQr1, bZr1, hr);
        f32x4 hi = {};
        hi = mm16(aQr0, bZi0, hi); hi = mm16(aQr1, bZi1, hi);
        hi = mm16(aQi0, bZr0, hi); hi = mm16(aQi1, bZr1, hi);
#pragma unroll
        for (int r = 0; r < 4; ++r) {
            const int l = w * 16 + fq * 4 + r;
            const int v = tv * 16 + fr;
            const float2 hin = *(const float2*)(h_intra +
                (((size_t)(b * L_ + l0 + l) * H_ + h) * 64 + v) * 2);
            hreg[tv][r][0] = hin.x + hr[r];
            hreg[tv][r][1] = hin.y + hi[r];
        }
    }

    // --- per-row GroupNorm stats (reduce over fr lanes within fq group) ---
    const float gw = gn_w[h], gbn = gn_b[h];
    float mean4[4], scl4[4];
#pragma unroll
    for (int r = 0; r < 4; ++r) {
        float s = 0.f, q = 0.f;
#pragma unroll
        for (int tv = 0; tv < 4; ++tv) {
            s += hreg[tv][r][0] + hreg[tv][r][1];
            q += hreg[tv][r][0] * hreg[tv][r][0] + hreg[tv][r][1] * hreg[tv][r][1];
        }
#pragma unroll
        for (int off = 1; off < 16; off <<= 1) {
            s += __shfl_xor(s, off);
            q += __shfl_xor(q, off);
        }
        const float m = s * (1.f / 128.f);
        const float var = q * (1.f / 128.f) - m * m;
        mean4[r] = m;
        scl4[r] = rsqrtf(var + EPS_) * gw;
    }

    // --- gate + write act (bf16) ---
#pragma unroll
    for (int tv = 0; tv < 4; ++tv) {
#pragma unroll
        for (int r = 0; r < 4; ++r) {
            const int l = w * 16 + fq * 4 + r;
            const int v = tv * 16 + fr;
            const size_t base = (size_t)(b * L_ + l0 + l) * 1024 + h * 128 + v * 2;
            const float2 gv = *(const float2*)(gbuf + base);
            const float hn0 = (hreg[tv][r][0] - mean4[r]) * scl4[r] + gbn;
            const float hn1 = (hreg[tv][r][1] - mean4[r]) * scl4[r] + gbn;
            const float a0 = hn0 * gv.x / (1.f + expf(-gv.x));
            const float a1 = hn1 * gv.y / (1.f + expf(-gv.y));
            ushort2 o; o.x = f2bf(a0); o.y = f2bf(a1);
            *(ushort2*)(act + base) = o;
        }
    }
}

// ---------------------------------------------------------------------------
// Launch
// ---------------------------------------------------------------------------
extern "C" void kernel_launch(void* const* d_in, const int* in_sizes, int n_in,
                              void* d_out, int out_size, void* d_ws, size_t ws_size,
                              hipStream_t stream)
{
    (void)in_sizes; (void)n_in; (void)ws_size;
    const float* x       = (const float*)d_in[0];
    const float* hidden  = (const float*)d_in[1];
    const float* w_qk    = (const float*)d_in[2];
    const float* b_qk    = (const float*)d_in[3];
    const float* w_v     = (const float*)d_in[4];
    const float* b_v     = (const float*)d_in[5];
    const float* w_g     = (const float*)d_in[6];
    const float* b_g     = (const float*)d_in[7];
    const float* w_a     = (const float*)d_in[8];
    const float* b_a     = (const float*)d_in[9];
    const float* w_y     = (const float*)d_in[10];
    const float* b_y     = (const float*)d_in[11];
    const float* gn_w    = (const float*)d_in[12];
    const float* gn_b    = (const float*)d_in[13];
    const float* p_angle = (const float*)d_in[14];

    float* y_out   = (float*)d_out;
    float* hid_out = (float*)d_out + (size_t)M_ * DIM_;
    const int hid_elems = out_size - M_ * DIM_;
    const int real_only = (hid_elems == B_ * H_ * DQK_ * DV_) ? 1 : 0;

    // ---- flat workspace layout (no aliasing) ----
    unsigned short* xb     = (unsigned short*)d_ws;            // [2048][1024]
    unsigned short* wall   = xb   + (size_t)2048 * 1024;       // [4224][1024]
    unsigned short* wyb    = wall + (size_t)4224 * 1024;       // [1024][1024]
    unsigned short* bqk    = wyb  + (size_t)1024 * 1024;       // [2048][2048] bf16
    unsigned short* bv     = bqk  + (size_t)2048 * 2048;       // [2048][1024] bf16
    unsigned short* actb   = bv   + (size_t)2048 * 1024;       // [2048][1024] bf16
    float* bg     = (float*)(actb + (size_t)2048 * 1024);      // [2048][1024]
    float* ba_pad = bg     + (size_t)2048 * 1024;              // [2048][128]
    float* babias = ba_pad + (size_t)2048 * 128;               // [128]
    float* bufW   = babias + 128;                              // [32][512][2]
    float* bufG   = bufW   + 32 * 512 * 2;                     // [32][8][2]
    float* bufZ   = bufG   + 512;                              // [256][4096][2]
    float* bufh   = bufZ   + (size_t)32 * 8 * 4096 * 2;        // [2048][8][64][2]

    cast_all<<<7177, 256, 0, stream>>>(x, w_qk, w_v, w_g, w_y, w_a, b_a,
                                       xb, wall, wyb, babias);

    // fused qk|v|g|a projection: N = 4224 (4096 + 128 pad tile), 8 waves/block
    gemm_proj<<<dim3(33, 16), 512, 0, stream>>>(
        xb, wall, b_qk, b_v, b_g, babias,
        bqk, bv, bg, ba_pad,
        2048, 3072, 4096,
        2048, 1024, 1024, 128,
        1, 1, 0, 0,
        M_, 4224, DIM_);

    chunkA_mfma<<<B_*H_*8, 256, 0, stream>>>(
        bqk, bv, ba_pad, p_angle, bufh, bufZ, bufG, bufW);
    scanB<<<B_*H_*8, 512, 0, stream>>>(
        bufZ, bufG, hidden, p_angle, hid_out, real_only);
    chunkC_gn<<<B_*H_*8, 256, 0, stream>>>(
        bqk, bufW, bufZ, p_angle, bufh, bg, gn_w, gn_b, actb);

    gemm_y<<<dim3(16, 32), 256, 0, stream>>>(
        actb, wyb, b_y, y_out, M_, DIM_, DIM_);
}

// Round 13
// 85.594 us; speedup vs baseline: 2.2169x; 1.0486x over previous
//
#include <hip/hip_runtime.h>
#include <cstdint>
#include <cstddef>

// Problem constants
#define B_   4
#define L_   512
#define DIM_ 1024
#define H_   8
#define DQK_ 64
#define DV_  64
#define M_   (B_ * L_)          // 2048 rows
#define EPS_ 1e-5f

typedef __attribute__((ext_vector_type(8))) short short8;
typedef __attribute__((ext_vector_type(4))) float f32x4;

// ---------------------------------------------------------------------------
// bf16 helpers
// ---------------------------------------------------------------------------
__device__ __forceinline__ unsigned short f2bf(float f) {
    uint32_t u = __float_as_uint(f);
    u += 0x7FFFu + ((u >> 16) & 1u);
    return (unsigned short)(u >> 16);
}
__device__ __forceinline__ float bf2f(unsigned short u) {
    return __uint_as_float((uint32_t)u << 16);
}

__device__ __forceinline__ f32x4 mm16(short8 a, short8 b, f32x4 c) {
    return __builtin_amdgcn_mfma_f32_16x16x32_bf16(a, b, c, 0, 0, 0);
}

// 64x64 bf16 plane with XOR swizzle: element (r,c) at byte r*128 + ((2c)^((r&7)<<4))
__device__ __forceinline__ int swoff(int r, int kb) {
    return r * 128 + (kb ^ ((r & 7) << 4));
}
__device__ __forceinline__ short8 frag(const unsigned short* p, int strip, int ks, int lane) {
    const int fr = lane & 15, fq = lane >> 4;
    const int r = strip * 16 + fr;
    return *(const short8*)((const char*)p + swoff(r, ks * 64 + fq * 16));
}

// ---------------------------------------------------------------------------
// Fused cast: x, w_qk|w_v|w_g|w_a -> wall, w_y -> bf16; b_a -> padded bias.
// ---------------------------------------------------------------------------
__global__ __launch_bounds__(256) void cast_all(
    const float* __restrict__ x, const float* __restrict__ wqk,
    const float* __restrict__ wv, const float* __restrict__ wg,
    const float* __restrict__ wy, const float* __restrict__ wa,
    const float* __restrict__ ba,
    unsigned short* __restrict__ xb, unsigned short* __restrict__ wall,
    unsigned short* __restrict__ wyb, float* __restrict__ babias)
{
    const int blk = blockIdx.x;
    if (blk == 7176) {
        if (threadIdx.x < 128)
            babias[threadIdx.x] = (threadIdx.x < 8) ? ba[threadIdx.x] : 0.f;
        return;
    }
    const float* src; unsigned short* dst; int base;
    if      (blk < 2048) { src = x;   dst = xb;                  base = blk; }
    else if (blk < 4096) { src = wqk; dst = wall;                base = blk - 2048; }
    else if (blk < 5120) { src = wv;  dst = wall + 2048 * 1024;  base = blk - 4096; }
    else if (blk < 6144) { src = wg;  dst = wall + 3072 * 1024;  base = blk - 5120; }
    else if (blk < 7168) { src = wy;  dst = wyb;                 base = blk - 6144; }
    else                 { src = wa;  dst = wall + 4096 * 1024;  base = blk - 7168; }
    const int i = base * 256 + threadIdx.x;
    const float4 v = ((const float4*)src)[i];
    ushort4 o;
    o.x = f2bf(v.x); o.y = f2bf(v.y); o.z = f2bf(v.z); o.w = f2bf(v.w);
    ((ushort4*)dst)[i] = o;
}

// ---------------------------------------------------------------------------
// bf16 MFMA GEMM: 128x128 tile, K-step=64 via two [128][32] planes per barrier
// pair (halves barrier count). 512 threads / 8 waves (2 row x 4 col).
// Each wave: 64x32 output, acc[4][2]. 4-range split epilogue, per-range dtype.
// ---------------------------------------------------------------------------
__device__ __forceinline__ void gload16(const void* g, void* l) {
    __builtin_amdgcn_global_load_lds(
        (const __attribute__((address_space(1))) unsigned int*)g,
        (__attribute__((address_space(3))) unsigned int*)l, 16, 0, 0);
}

__global__ __launch_bounds__(512) void gemm_proj(
    const unsigned short* __restrict__ A, const unsigned short* __restrict__ W,
    const float* __restrict__ bias0, const float* __restrict__ bias1,
    const float* __restrict__ bias2, const float* __restrict__ bias3,
    void* __restrict__ C0, void* __restrict__ C1,
    void* __restrict__ C2, void* __restrict__ C3,
    int n1, int n2, int n3,
    int ld0, int ld1, int ld2, int ld3,
    int bf0, int bf1, int bf2, int bf3,
    int M, int N, int K)
{
    __shared__ unsigned short sA[2][128 * 32];
    __shared__ unsigned short sB[2][128 * 32];

    const int t    = threadIdx.x;
    const int lane = t & 63;
    const int wv   = t >> 6;          // 0..7
    const int bm   = blockIdx.y * 128;
    const int bn   = blockIdx.x * 128;
    const int wr   = wv >> 2;         // 0..1  (64-row half)
    const int wc   = wv & 3;          // 0..3  (32-col quarter)
    const int fr   = lane & 15;
    const int fq   = lane >> 4;
    const int srow = lane >> 2;
    const int ske  = (lane & 3) * 8;

    f32x4 acc[4][2] = {};

    for (int k0 = 0; k0 < K; k0 += 64) {
#pragma unroll
        for (int p = 0; p < 2; ++p) {
            gload16(A + (size_t)(bm + wv * 16 + srow) * K + k0 + p * 32 + ske,
                    (char*)sA[p] + wv * 1024);
            gload16(W + (size_t)(bn + wv * 16 + srow) * K + k0 + p * 32 + ske,
                    (char*)sB[p] + wv * 1024);
        }
        __syncthreads();

#pragma unroll
        for (int p = 0; p < 2; ++p) {
            short8 af[4], bf[2];
#pragma unroll
            for (int mi = 0; mi < 4; ++mi)
                af[mi] = *(const short8*)&sA[p][(wr * 64 + mi * 16 + fr) * 32 + fq * 8];
#pragma unroll
            for (int ni = 0; ni < 2; ++ni)
                bf[ni] = *(const short8*)&sB[p][(wc * 32 + ni * 16 + fr) * 32 + fq * 8];
#pragma unroll
            for (int mi = 0; mi < 4; ++mi)
#pragma unroll
                for (int ni = 0; ni < 2; ++ni)
                    acc[mi][ni] = mm16(af[mi], bf[ni], acc[mi][ni]);
        }
        __syncthreads();
    }

    void* Cb; const float* bb; int coff, ldc, isbf;
    if      (bn < n1) { Cb = C0; bb = bias0; coff = 0;  ldc = ld0; isbf = bf0; }
    else if (bn < n2) { Cb = C1; bb = bias1; coff = n1; ldc = ld1; isbf = bf1; }
    else if (bn < n3) { Cb = C2; bb = bias2; coff = n2; ldc = ld2; isbf = bf2; }
    else              { Cb = C3; bb = bias3; coff = n3; ldc = ld3; isbf = bf3; }

#pragma unroll
    for (int mi = 0; mi < 4; ++mi)
#pragma unroll
        for (int ni = 0; ni < 2; ++ni) {
            const int col = bn + wc * 32 + ni * 16 + fr - coff;
            const float bv = bb[col];
#pragma unroll
            for (int r = 0; r < 4; ++r) {
                const int row = bm + wr * 64 + mi * 16 + fq * 4 + r;
                const float val = acc[mi][ni][r] + bv;
                if (isbf)
                    ((unsigned short*)Cb)[(size_t)row * ldc + col] = f2bf(val);
                else
                    ((float*)Cb)[(size_t)row * ldc + col] = val;
            }
        }
}

// ---------------------------------------------------------------------------
// y GEMM: 64x64 tile, K-step=64 (two planes), 4 waves -> grid (16,32).
// ---------------------------------------------------------------------------
__global__ __launch_bounds__(256) void gemm_y(
    const unsigned short* __restrict__ A, const unsigned short* __restrict__ W,
    const float* __restrict__ bias, float* __restrict__ C,
    int M, int N, int K)
{
    __shared__ unsigned short sA[2][64 * 32];
    __shared__ unsigned short sB[2][64 * 32];

    const int t    = threadIdx.x;
    const int lane = t & 63;
    const int wv   = t >> 6;          // 0..3
    const int bm   = blockIdx.y * 64;
    const int bn   = blockIdx.x * 64;
    const int wr   = wv >> 1;         // 0..1
    const int wc   = wv & 1;          // 0..1
    const int fr   = lane & 15;
    const int fq   = lane >> 4;
    const int srow = lane >> 2;
    const int ske  = (lane & 3) * 8;

    f32x4 acc[2][2] = {};

    for (int k0 = 0; k0 < K; k0 += 64) {
#pragma unroll
        for (int p = 0; p < 2; ++p) {
            gload16(A + (size_t)(bm + wv * 16 + srow) * K + k0 + p * 32 + ske,
                    (char*)sA[p] + wv * 1024);
            gload16(W + (size_t)(bn + wv * 16 + srow) * K + k0 + p * 32 + ske,
                    (char*)sB[p] + wv * 1024);
        }
        __syncthreads();

#pragma unroll
        for (int p = 0; p < 2; ++p) {
            short8 af[2], bf[2];
#pragma unroll
            for (int mi = 0; mi < 2; ++mi)
                af[mi] = *(const short8*)&sA[p][(wr * 32 + mi * 16 + fr) * 32 + fq * 8];
#pragma unroll
            for (int ni = 0; ni < 2; ++ni)
                bf[ni] = *(const short8*)&sB[p][(wc * 32 + ni * 16 + fr) * 32 + fq * 8];
#pragma unroll
            for (int mi = 0; mi < 2; ++mi)
#pragma unroll
                for (int ni = 0; ni < 2; ++ni)
                    acc[mi][ni] = mm16(af[mi], bf[ni], acc[mi][ni]);
        }
        __syncthreads();
    }

#pragma unroll
    for (int mi = 0; mi < 2; ++mi)
#pragma unroll
        for (int ni = 0; ni < 2; ++ni) {
            const int col = bn + wc * 32 + ni * 16 + fr;
            const float bv = bias[col];
#pragma unroll
            for (int r = 0; r < 4; ++r) {
                const int row = bm + wr * 32 + mi * 16 + fq * 4 + r;
                C[(size_t)row * N + col] = acc[mi][ni][r] + bv;
            }
        }
}

// ---------------------------------------------------------------------------
// chunkA: one block per (b,h,chunk), 256 threads / 4 waves.
// qk, v inputs are bf16. Phase folded into load transform.
// P = Q~K~^T (masked), H = P V, Z = K~^T V via mfma_16x16x32_bf16.
// ---------------------------------------------------------------------------
__global__ __launch_bounds__(256) void chunkA_mfma(
    const unsigned short* __restrict__ qk_bf, const unsigned short* __restrict__ v_bf,
    const float* __restrict__ a_pad, const float* __restrict__ p_angle,
    float* __restrict__ h_pre, float* __restrict__ Zloc,
    float* __restrict__ Gbuf, float* __restrict__ Wbuf)
{
    const int blk = blockIdx.x;
    const int c  = blk & 7;
    const int bh = blk >> 3;
    const int b = bh >> 3, h = bh & 7;
    const int t = threadIdx.x;
    const int l0 = c * 64;

    __shared__ unsigned short pQr[4096], pQi[4096];   // later reused as Pr, Pi
    __shared__ unsigned short pKr[4096], pKi[4096];   // [m][i]
    __shared__ unsigned short pKtr[4096], pKti[4096]; // [i][m]
    __shared__ unsigned short pVtr[4096], pVti[4096]; // [v][m]
    __shared__ float sW[64][4];
    __shared__ float sTh[64];

    // --- lambda cumprod scan (wave 0) + p_angle stash ---
    if (t < 64) {
        sTh[t] = p_angle[h * DQK_ + t];
        const float th0 = p_angle[h * DQK_];
        const float a = a_pad[((size_t)(b * L_) + l0 + t) * 128 + h];
        float sa, ca; __sincosf(a * th0, &sa, &ca);
        const float em = expf(-th0), ep = expf(th0);
        float lr = em * ca, li = em * sa;      // lambda
        float ir = ep * ca, ii = -ep * sa;     // 1/lambda
#pragma unroll
        for (int off = 1; off < 64; off <<= 1) {
            const float plr = __shfl_up(lr, off);
            const float pli = __shfl_up(li, off);
            const float pir = __shfl_up(ir, off);
            const float pii = __shfl_up(ii, off);
            if (t >= off) {
                float nr = lr * plr - li * pli;
                float ni = lr * pli + li * plr;
                lr = nr; li = ni;
                nr = ir * pir - ii * pii;
                ni = ir * pii + ii * pir;
                ir = nr; ii = ni;
            }
        }
        sW[t][0] = lr; sW[t][1] = li; sW[t][2] = ir; sW[t][3] = ii;
        Wbuf[((size_t)bh * L_ + l0 + t) * 2 + 0] = lr;
        Wbuf[((size_t)bh * L_ + l0 + t) * 2 + 1] = li;
        if (t == 63) {
            Gbuf[(bh * 8 + c) * 2 + 0] = lr;
            Gbuf[(bh * 8 + c) * 2 + 1] = li;
        }
    }
    __syncthreads();

    // --- load planes: thread t owns (row = t>>2, 16-col segment cs = t&3) ---
    const int row = t >> 2, cs = t & 3;
    {
        const float wr = sW[row][0], wi = sW[row][1];
        const float xr = sW[row][2], xi = sW[row][3];
        const float lf = (float)(l0 + row);
        unsigned short qr16[16], qi16[16], kr16[16], ki16[16];
        const unsigned short* qg = qk_bf +
            (size_t)(b * L_ + l0 + row) * 2048 + h * 256 + cs * 64;
#pragma unroll
        for (int j = 0; j < 16; ++j) {
            const ushort4 qu = *(const ushort4*)(qg + j * 4);
            const float qre = bf2f(qu.x), qim = bf2f(qu.y);
            const float kre = bf2f(qu.z), kim = bf2f(qu.w);
            float sn, cn; __sincosf(sTh[cs * 16 + j] * lf, &sn, &cn);
            // q~ = q * e^{+i l th} * W ;  k~ = k * e^{-i l th} * invW
            const float fqr = cn * wr - sn * wi, fqi = cn * wi + sn * wr;
            const float fkr = cn * xr + sn * xi, fki = cn * xi - sn * xr;
            qr16[j] = f2bf(qre * fqr - qim * fqi);
            qi16[j] = f2bf(qre * fqi + qim * fqr);
            const float kr = kre * fkr - kim * fki;
            const float ki = kre * fki + kim * fkr;
            kr16[j] = f2bf(kr); ki16[j] = f2bf(ki);
            const int i = cs * 16 + j;      // transposed K writes [i][m=row]
            const int ob = swoff(i, 2 * row);
            *(unsigned short*)((char*)pKtr + ob) = kr16[j];
            *(unsigned short*)((char*)pKti + ob) = ki16[j];
        }
        const int kb0 = 32 * cs;
        short8 s0, s1;
#pragma unroll
        for (int j = 0; j < 8; ++j) { s0[j] = (short)qr16[j]; s1[j] = (short)qr16[8 + j]; }
        *(short8*)((char*)pQr + swoff(row, kb0))      = s0;
        *(short8*)((char*)pQr + swoff(row, kb0 + 16)) = s1;
#pragma unroll
        for (int j = 0; j < 8; ++j) { s0[j] = (short)qi16[j]; s1[j] = (short)qi16[8 + j]; }
        *(short8*)((char*)pQi + swoff(row, kb0))      = s0;
        *(short8*)((char*)pQi + swoff(row, kb0 + 16)) = s1;
#pragma unroll
        for (int j = 0; j < 8; ++j) { s0[j] = (short)kr16[j]; s1[j] = (short)kr16[8 + j]; }
        *(short8*)((char*)pKr + swoff(row, kb0))      = s0;
        *(short8*)((char*)pKr + swoff(row, kb0 + 16)) = s1;
#pragma unroll
        for (int j = 0; j < 8; ++j) { s0[j] = (short)ki16[j]; s1[j] = (short)ki16[8 + j]; }
        *(short8*)((char*)pKi + swoff(row, kb0))      = s0;
        *(short8*)((char*)pKi + swoff(row, kb0 + 16)) = s1;

        const unsigned short* vg = v_bf +
            (size_t)(b * L_ + l0 + row) * 1024 + h * 128 + cs * 32;
#pragma unroll
        for (int j = 0; j < 16; ++j) {
            const ushort2 vv = *(const ushort2*)(vg + j * 2);
            const int v = cs * 16 + j;      // transposed V writes [v][m=row]
            const int ob = swoff(v, 2 * row);
            *(unsigned short*)((char*)pVtr + ob) = vv.x;
            *(unsigned short*)((char*)pVti + ob) = vv.y;
        }
    }
    __syncthreads();

    // --- P = Q~ K~^T (wave w owns l-strip w) ---
    const int w = t >> 6, lane = t & 63;
    const int fr = lane & 15, fq = lane >> 4;
    short8 aQr0 = frag(pQr, w, 0, lane), aQr1 = frag(pQr, w, 1, lane);
    short8 aQi0 = frag(pQi, w, 0, lane), aQi1 = frag(pQi, w, 1, lane);
    f32x4 Pr[4], Pi[4];
#pragma unroll
    for (int tm = 0; tm < 4; ++tm) {
        short8 bKr0 = frag(pKr, tm, 0, lane), bKr1 = frag(pKr, tm, 1, lane);
        short8 bKi0 = frag(pKi, tm, 0, lane), bKi1 = frag(pKi, tm, 1, lane);
        f32x4 tmp = {};
        tmp = mm16(aQi0, bKi0, tmp); tmp = mm16(aQi1, bKi1, tmp);
        tmp = -tmp;
        tmp = mm16(aQr0, bKr0, tmp); tmp = mm16(aQr1, bKr1, tmp);
        Pr[tm] = tmp;
        f32x4 t2 = {};
        t2 = mm16(aQr0, bKi0, t2); t2 = mm16(aQr1, bKi1, t2);
        t2 = mm16(aQi0, bKr0, t2); t2 = mm16(aQi1, bKr1, t2);
        Pi[tm] = t2;
    }
    // mask (keep m<=l) and write P into pQr/pQi (wave-own rows only: no barrier)
#pragma unroll
    for (int tm = 0; tm < 4; ++tm) {
        const int m = tm * 16 + fr;
#pragma unroll
        for (int r = 0; r < 4; ++r) {
            const int l = w * 16 + fq * 4 + r;
            const int ob = swoff(l, 2 * m);
            const float prv = (m <= l) ? Pr[tm][r] : 0.f;
            const float piv = (m <= l) ? Pi[tm][r] : 0.f;
            *(unsigned short*)((char*)pQr + ob) = f2bf(prv);
            *(unsigned short*)((char*)pQi + ob) = f2bf(piv);
        }
    }

    // --- H = P V and Z = K~^T V (shared V fragments) ---
    short8 aPr0 = frag(pQr, w, 0, lane), aPr1 = frag(pQr, w, 1, lane);
    short8 aPi0 = frag(pQi, w, 0, lane), aPi1 = frag(pQi, w, 1, lane);
    short8 aKt_r0 = frag(pKtr, w, 0, lane), aKt_r1 = frag(pKtr, w, 1, lane);
    short8 aKt_i0 = frag(pKti, w, 0, lane), aKt_i1 = frag(pKti, w, 1, lane);
    const float Gr = sW[63][0], Gi = sW[63][1];
#pragma unroll
    for (int tv = 0; tv < 4; ++tv) {
        short8 bVr0 = frag(pVtr, tv, 0, lane), bVr1 = frag(pVtr, tv, 1, lane);
        short8 bVi0 = frag(pVti, tv, 0, lane), bVi1 = frag(pVti, tv, 1, lane);
        f32x4 hr = {};
        hr = mm16(aPi0, bVi0, hr); hr = mm16(aPi1, bVi1, hr);
        hr = -hr;
        hr = mm16(aPr0, bVr0, hr); hr = mm16(aPr1, bVr1, hr);
        f32x4 hi = {};
        hi = mm16(aPr0, bVi0, hi); hi = mm16(aPr1, bVi1, hi);
        hi = mm16(aPi0, bVr0, hi); hi = mm16(aPi1, bVr1, hi);
        f32x4 zr = {};
        zr = mm16(aKt_i0, bVi0, zr); zr = mm16(aKt_i1, bVi1, zr);
        zr = -zr;
        zr = mm16(aKt_r0, bVr0, zr); zr = mm16(aKt_r1, bVr1, zr);
        f32x4 zi = {};
        zi = mm16(aKt_r0, bVi0, zi); zi = mm16(aKt_r1, bVi1, zi);
        zi = mm16(aKt_i0, bVr0, zi); zi = mm16(aKt_i1, bVr1, zi);
#pragma unroll
        for (int r = 0; r < 4; ++r) {
            const int lrow = w * 16 + fq * 4 + r;    // l for H, i for Z
            const int v = tv * 16 + fr;
            *(float2*)(h_pre + (((size_t)(b * L_ + l0 + lrow) * H_ + h) * 64 + v) * 2)
                = make_float2(hr[r], hi[r]);
            float* zp = Zloc + (((size_t)(bh * 8 + c) * 4096) + lrow * 64 + v) * 2;
            zp[0] = Gr * zr[r] - Gi * zi[r];
            zp[1] = Gr * zi[r] + Gi * zr[r];
        }
    }
}

// ---------------------------------------------------------------------------
// scanB: sequential over 8 chunks, parallel over entries. In-place Zloc->Zin.
// ---------------------------------------------------------------------------
__global__ __launch_bounds__(512) void scanB(
    float* __restrict__ Zbuf, const float* __restrict__ Gbuf,
    const float* __restrict__ hidden, const float* __restrict__ p_angle,
    float* __restrict__ hid_out, int real_only)
{
    const int bid = blockIdx.x;
    const int bh = bid >> 3, part = bid & 7;
    const int h = bh & 7;
    const int e = part * 512 + threadIdx.x;
    const int i = e >> 6;
    const float th = p_angle[h * 64 + i];
    float s, c; __sincosf(th, &s, &c);
    const float2 h0 = *(const float2*)(hidden + ((size_t)bh * 4096 + e) * 2);
    float zr = h0.x * c - h0.y * s;
    float zi = h0.x * s + h0.y * c;
#pragma unroll
    for (int ch = 0; ch < 8; ++ch) {
        float* zp = Zbuf + ((size_t)(bh * 8 + ch) * 4096 + e) * 2;
        const float zlr = zp[0], zli = zp[1];
        zp[0] = zr; zp[1] = zi;
        const float gr = Gbuf[(bh * 8 + ch) * 2], gi = Gbuf[(bh * 8 + ch) * 2 + 1];
        const float nr = gr * zr - gi * zi + zlr;
        const float ni = gr * zi + gi * zr + zli;
        zr = nr; zi = ni;
    }
    float s2, c2; __sincosf(th * (float)(L_ - 1), &s2, &c2);
    const float outr = zr * c2 - zi * s2;
    const float outi = zr * s2 + zi * c2;
    if (real_only) {
        hid_out[(size_t)bh * 4096 + e] = outr;
    } else {
        hid_out[((size_t)bh * 4096 + e) * 2 + 0] = outr;
        hid_out[((size_t)bh * 4096 + e) * 2 + 1] = outi;
    }
}

// ---------------------------------------------------------------------------
// chunkC_gn: h = h_intra + Q~.Zin, fused GroupNorm + SiLU gate -> act bf16.
// qk input is bf16.
// ---------------------------------------------------------------------------
__global__ __launch_bounds__(256) void chunkC_gn(
    const unsigned short* __restrict__ qk_bf, const float* __restrict__ Wbuf,
    const float* __restrict__ Zin, const float* __restrict__ p_angle,
    const float* __restrict__ h_intra, const float* __restrict__ gbuf,
    const float* __restrict__ gn_w, const float* __restrict__ gn_b,
    unsigned short* __restrict__ act)
{
    const int blk = blockIdx.x;
    const int c = blk & 7, bh = blk >> 3;
    const int b = bh >> 3, h = bh & 7;
    const int t = threadIdx.x;
    const int l0 = c * 64;

    __shared__ unsigned short pQr[4096], pQi[4096];   // [l][i]
    __shared__ unsigned short pZtr[4096], pZti[4096]; // [v][i]
    __shared__ float sTh[64];

    if (t < 64) sTh[t] = p_angle[h * 64 + t];
    __syncthreads();

    const int row = t >> 2, cs = t & 3;
    {
        const float wr = Wbuf[((size_t)bh * L_ + l0 + row) * 2];
        const float wi = Wbuf[((size_t)bh * L_ + l0 + row) * 2 + 1];
        const float lf = (float)(l0 + row);
        unsigned short qr16[16], qi16[16];
        const unsigned short* qg = qk_bf +
            (size_t)(b * L_ + l0 + row) * 2048 + h * 256 + cs * 64;
#pragma unroll
        for (int j = 0; j < 16; ++j) {
            const ushort4 qu = *(const ushort4*)(qg + j * 4);
            const float qre = bf2f(qu.x), qim = bf2f(qu.y);
            float sn, cn; __sincosf(sTh[cs * 16 + j] * lf, &sn, &cn);
            const float fqr = cn * wr - sn * wi, fqi = cn * wi + sn * wr;
            qr16[j] = f2bf(qre * fqr - qim * fqi);
            qi16[j] = f2bf(qre * fqi + qim * fqr);
        }
        const int kb0 = 32 * cs;
        short8 s0, s1;
#pragma unroll
        for (int j = 0; j < 8; ++j) { s0[j] = (short)qr16[j]; s1[j] = (short)qr16[8 + j]; }
        *(short8*)((char*)pQr + swoff(row, kb0))      = s0;
        *(short8*)((char*)pQr + swoff(row, kb0 + 16)) = s1;
#pragma unroll
        for (int j = 0; j < 8; ++j) { s0[j] = (short)qi16[j]; s1[j] = (short)qi16[8 + j]; }
        *(short8*)((char*)pQi + swoff(row, kb0))      = s0;
        *(short8*)((char*)pQi + swoff(row, kb0 + 16)) = s1;

        // Zin row i=row, v-seg: write transposed [v][i]
        const float2* zg = (const float2*)(Zin +
            ((size_t)(bh * 8 + c) * 4096 + row * 64 + cs * 16) * 2);
#pragma unroll
        for (int j = 0; j < 16; ++j) {
            const float2 z = zg[j];
            const int v = cs * 16 + j;
            const int ob = swoff(v, 2 * row);
            *(unsigned short*)((char*)pZtr + ob) = f2bf(z.x);
            *(unsigned short*)((char*)pZti + ob) = f2bf(z.y);
        }
    }
    __syncthreads();

    const int w = t >> 6, lane = t & 63;
    const int fr = lane & 15, fq = lane >> 4;
    short8 aQr0 = frag(pQr, w, 0, lane), aQr1 = frag(pQr, w, 1, lane);
    short8 aQi0 = frag(pQi, w, 0, lane), aQi1 = frag(pQi, w, 1, lane);

    float hreg[4][4][2];   // [tv][r][ri]
#pragma unroll
    for (int tv = 0; tv < 4; ++tv) {
        short8 bZr0 = frag(pZtr, tv, 0, lane), bZr1 = frag(pZtr, tv, 1, lane);
        short8 bZi0 = frag(pZti, tv, 0, lane), bZi1 = frag(pZti, tv, 1, lane);
        f32x4 hr = {};
        hr = mm16(aQi0, bZi0, hr); hr = mm16(aQi1, bZi1, hr);
        hr = -hr;
        hr = mm16(aQr0, bZr0, hr); hr = mm16(aQr1, bZr1, hr);
        f32x4 hi = {};
        hi = mm16(aQr0, bZi0, hi); hi = mm16(aQr1, bZi1, hi);
        hi = mm16(aQi0, bZr0, hi); hi = mm16(aQi1, bZr1, hi);
#pragma unroll
        for (int r = 0; r < 4; ++r) {
            const int l = w * 16 + fq * 4 + r;
            const int v = tv * 16 + fr;
            const float2 hin = *(const float2*)(h_intra +
                (((size_t)(b * L_ + l0 + l) * H_ + h) * 64 + v) * 2);
            hreg[tv][r][0] = hin.x + hr[r];
            hreg[tv][r][1] = hin.y + hi[r];
        }
    }

    // --- per-row GroupNorm stats (reduce over fr lanes within fq group) ---
    const float gw = gn_w[h], gbn = gn_b[h];
    float mean4[4], scl4[4];
#pragma unroll
    for (int r = 0; r < 4; ++r) {
        float s = 0.f, q = 0.f;
#pragma unroll
        for (int tv = 0; tv < 4; ++tv) {
            s += hreg[tv][r][0] + hreg[tv][r][1];
            q += hreg[tv][r][0] * hreg[tv][r][0] + hreg[tv][r][1] * hreg[tv][r][1];
        }
#pragma unroll
        for (int off = 1; off < 16; off <<= 1) {
            s += __shfl_xor(s, off);
            q += __shfl_xor(q, off);
        }
        const float m = s * (1.f / 128.f);
        const float var = q * (1.f / 128.f) - m * m;
        mean4[r] = m;
        scl4[r] = rsqrtf(var + EPS_) * gw;
    }

    // --- gate + write act (bf16) ---
#pragma unroll
    for (int tv = 0; tv < 4; ++tv) {
#pragma unroll
        for (int r = 0; r < 4; ++r) {
            const int l = w * 16 + fq * 4 + r;
            const int v = tv * 16 + fr;
            const size_t base = (size_t)(b * L_ + l0 + l) * 1024 + h * 128 + v * 2;
            const float2 gv = *(const float2*)(gbuf + base);
            const float hn0 = (hreg[tv][r][0] - mean4[r]) * scl4[r] + gbn;
            const float hn1 = (hreg[tv][r][1] - mean4[r]) * scl4[r] + gbn;
            const float a0 = hn0 * gv.x / (1.f + expf(-gv.x));
            const float a1 = hn1 * gv.y / (1.f + expf(-gv.y));
            ushort2 o; o.x = f2bf(a0); o.y = f2bf(a1);
            *(ushort2*)(act + base) = o;
        }
    }
}

// ---------------------------------------------------------------------------
// Launch
// ---------------------------------------------------------------------------
extern "C" void kernel_launch(void* const* d_in, const int* in_sizes, int n_in,
                              void* d_out, int out_size, void* d_ws, size_t ws_size,
                              hipStream_t stream)
{
    (void)in_sizes; (void)n_in; (void)ws_size;
    const float* x       = (const float*)d_in[0];
    const float* hidden  = (const float*)d_in[1];
    const float* w_qk    = (const float*)d_in[2];
    const float* b_qk    = (const float*)d_in[3];
    const float* w_v     = (const float*)d_in[4];
    const float* b_v     = (const float*)d_in[5];
    const float* w_g     = (const float*)d_in[6];
    const float* b_g     = (const float*)d_in[7];
    const float* w_a     = (const float*)d_in[8];
    const float* b_a     = (const float*)d_in[9];
    const float* w_y     = (const float*)d_in[10];
    const float* b_y     = (const float*)d_in[11];
    const float* gn_w    = (const float*)d_in[12];
    const float* gn_b    = (const float*)d_in[13];
    const float* p_angle = (const float*)d_in[14];

    float* y_out   = (float*)d_out;
    float* hid_out = (float*)d_out + (size_t)M_ * DIM_;
    const int hid_elems = out_size - M_ * DIM_;
    const int real_only = (hid_elems == B_ * H_ * DQK_ * DV_) ? 1 : 0;

    // ---- flat workspace layout (no aliasing) ----
    unsigned short* xb     = (unsigned short*)d_ws;            // [2048][1024]
    unsigned short* wall   = xb   + (size_t)2048 * 1024;       // [4224][1024]
    unsigned short* wyb    = wall + (size_t)4224 * 1024;       // [1024][1024]
    unsigned short* bqk    = wyb  + (size_t)1024 * 1024;       // [2048][2048] bf16
    unsigned short* bv     = bqk  + (size_t)2048 * 2048;       // [2048][1024] bf16
    unsigned short* actb   = bv   + (size_t)2048 * 1024;       // [2048][1024] bf16
    float* bg     = (float*)(actb + (size_t)2048 * 1024);      // [2048][1024]
    float* ba_pad = bg     + (size_t)2048 * 1024;              // [2048][128]
    float* babias = ba_pad + (size_t)2048 * 128;               // [128]
    float* bufW   = babias + 128;                              // [32][512][2]
    float* bufG   = bufW   + 32 * 512 * 2;                     // [32][8][2]
    float* bufZ   = bufG   + 512;                              // [256][4096][2]
    float* bufh   = bufZ   + (size_t)32 * 8 * 4096 * 2;        // [2048][8][64][2]

    cast_all<<<7177, 256, 0, stream>>>(x, w_qk, w_v, w_g, w_y, w_a, b_a,
                                       xb, wall, wyb, babias);

    // fused qk|v|g|a projection: N = 4224 (4096 + 128 pad tile), 8 waves/block
    gemm_proj<<<dim3(33, 16), 512, 0, stream>>>(
        xb, wall, b_qk, b_v, b_g, babias,
        bqk, bv, bg, ba_pad,
        2048, 3072, 4096,
        2048, 1024, 1024, 128,
        1, 1, 0, 0,
        M_, 4224, DIM_);

    chunkA_mfma<<<B_*H_*8, 256, 0, stream>>>(
        bqk, bv, ba_pad, p_angle, bufh, bufZ, bufG, bufW);
    scanB<<<B_*H_*8, 512, 0, stream>>>(
        bufZ, bufG, hidden, p_angle, hid_out, real_only);
    chunkC_gn<<<B_*H_*8, 256, 0, stream>>>(
        bqk, bufW, bufZ, p_angle, bufh, bg, gn_w, gn_b, actb);

    gemm_y<<<dim3(16, 32), 256, 0, stream>>>(
        actb, wyb, b_y, y_out, M_, DIM_, DIM_);
}